// Round 1
// baseline (529.613 us; speedup 1.0000x reference)
//
#include <hip/hip_runtime.h>

#define B_ROWS  262144
#define N_NEG   1310720
#define STILE   4096
#define SBLK    320          // N_NEG / STILE

// ---------------- ws layout (bytes) ----------------
#define OFF_K0    0u
#define OFF_K1    5242880u
#define OFF_V0    10485760u
#define OFF_V1    15728640u
#define OFF_HIST  20971520u   // 256*320*4 = 327680
#define OFF_TOT   21299200u   // 256*4
#define OFF_TOTX  21300224u   // 256*4
#define OFF_AMAXT 21301248u   // 262144*4
#define OFF_CONFT 22349824u
#define OFF_AMAXF 23398400u
#define OFF_CONFF 24446976u
#define OFF_POSD  25495552u
#define OFF_ACC   26544128u   // 8 doubles
#define WS_NEEDED 26544192u

struct U2 { unsigned a, b; };

// Threefry-2x32, 20 rounds — matches jax/_src/prng.py threefry2x32.
__host__ __device__ inline U2 tf2x32(unsigned k0, unsigned k1, unsigned c0, unsigned c1) {
  unsigned ks2 = k0 ^ k1 ^ 0x1BD11BDAu;
  unsigned x0 = c0 + k0, x1 = c1 + k1;
#define ROTL(x,d) (((x) << (d)) | ((x) >> (32 - (d))))
#define R4(r0,r1,r2,r3) \
  x0 += x1; x1 = ROTL(x1, r0); x1 ^= x0; \
  x0 += x1; x1 = ROTL(x1, r1); x1 ^= x0; \
  x0 += x1; x1 = ROTL(x1, r2); x1 ^= x0; \
  x0 += x1; x1 = ROTL(x1, r3); x1 ^= x0;
  R4(13,15,26,6)   x0 += k1;  x1 += ks2 + 1u;
  R4(17,29,16,24)  x0 += ks2; x1 += k0  + 2u;
  R4(13,15,26,6)   x0 += k0;  x1 += k1  + 3u;
  R4(17,29,16,24)  x0 += k1;  x1 += ks2 + 4u;
  R4(13,15,26,6)   x0 += ks2; x1 += k0  + 5u;
#undef R4
#undef ROTL
  return U2{x0, x1};
}

// keys[i] = bits1^bits2 of cipher(subkey,(0,i))  (partitionable 32-bit draw)
__global__ __launch_bounds__(256)
void k_keygen(unsigned* __restrict__ keys, unsigned* __restrict__ vals,
              unsigned k0, unsigned k1, int writeVals) {
  unsigned i = blockIdx.x * 256 + threadIdx.x;
  U2 c = tf2x32(k0, k1, 0u, i);
  keys[i] = c.a ^ c.b;
  if (writeVals) vals[i] = i;
}

__global__ __launch_bounds__(256)
void k_hist(const unsigned* __restrict__ keys, unsigned* __restrict__ hist, int shift) {
  __shared__ unsigned h[256];
  int t = threadIdx.x;
  h[t] = 0;
  __syncthreads();
  size_t base = (size_t)blockIdx.x * STILE;
  for (int it = 0; it < 16; ++it) {
    unsigned k = keys[base + it * 256 + t];
    atomicAdd(&h[(k >> shift) & 255u], 1u);
  }
  __syncthreads();
  hist[(size_t)t * SBLK + blockIdx.x] = h[t];
}

// per-digit exclusive scan across the 320 blocks (in place), totals per digit
__global__ void k_scan_rows(unsigned* __restrict__ hist, unsigned* __restrict__ tot) {
  int d = blockIdx.x, lane = threadIdx.x;   // 64 threads
  unsigned running = 0;
  for (int it = 0; it < SBLK / 64; ++it) {
    size_t idx = (size_t)d * SBLK + it * 64 + lane;
    unsigned v = hist[idx];
    unsigned incl = v;
    for (int o = 1; o < 64; o <<= 1) { unsigned x = __shfl_up(incl, o); if (lane >= o) incl += x; }
    hist[idx] = running + (incl - v);
    running += __shfl(incl, 63);
  }
  if (lane == 0) tot[d] = running;
}

__global__ void k_scan_totals(const unsigned* __restrict__ tot, unsigned* __restrict__ totx) {
  __shared__ unsigned s[256];
  int t = threadIdx.x;
  unsigned v = tot[t];
  s[t] = v;
  __syncthreads();
  for (int o = 1; o < 256; o <<= 1) {
    unsigned x = (t >= o) ? s[t - o] : 0u;
    __syncthreads();
    s[t] += x;
    __syncthreads();
  }
  totx[t] = s[t] - v;
}

// stable scatter: wave-iteration ordering + 8-ballot digit match ranking
__global__ __launch_bounds__(256)
void k_scatter(const unsigned* __restrict__ keysIn, const unsigned* __restrict__ valsIn,
               unsigned* __restrict__ keysOut, unsigned* __restrict__ valsOut,
               const unsigned* __restrict__ hist, const unsigned* __restrict__ totx, int shift) {
  __shared__ unsigned wcnt[4][256];
  __shared__ unsigned wstart[4][256];
  int t = threadIdx.x, w = t >> 6, lane = t & 63;
  for (int j = 0; j < 4; ++j) wcnt[j][t] = 0;
  __syncthreads();
  size_t base = (size_t)blockIdx.x * STILE + (size_t)w * 1024;
  unsigned kv[16], dg[16];
#pragma unroll
  for (int it = 0; it < 16; ++it) {
    unsigned k = keysIn[base + it * 64 + lane];
    kv[it] = k;
    unsigned d = (k >> shift) & 255u;
    dg[it] = d;
    atomicAdd(&wcnt[w][d], 1u);
  }
  __syncthreads();
  {
    unsigned c0 = wcnt[0][t], c1 = wcnt[1][t], c2 = wcnt[2][t];
    unsigned g = totx[t] + hist[(size_t)t * SBLK + blockIdx.x];
    wstart[0][t] = g;
    wstart[1][t] = g + c0;
    wstart[2][t] = g + c0 + c1;
    wstart[3][t] = g + c0 + c1 + c2;
  }
  __syncthreads();
  for (int it = 0; it < 16; ++it) {
    unsigned k = kv[it], d = dg[it];
    unsigned v = valsIn[base + it * 64 + lane];
    unsigned long long m = ~0ull;
#pragma unroll
    for (int bb = 0; bb < 8; ++bb) {
      unsigned long long bal = __ballot((d >> bb) & 1u);
      m &= ((d >> bb) & 1u) ? bal : ~bal;
    }
    int leader = __ffsll((unsigned long long)m) - 1;
    int rank = __popcll(m & ((1ull << lane) - 1ull));
    unsigned old = 0;
    if (lane == leader) old = atomicAdd(&wstart[w][d], (unsigned)__popcll(m));
    old = __shfl(old, leader);
    unsigned pos = old + (unsigned)rank;
    keysOut[pos] = k;
    valsOut[pos] = v;
  }
}

// ---------------- loss kernels ----------------
template <int N>
__device__ inline void block_acc(double* dst, const double* v) {
  __shared__ double sh[N][4];
  int lane = threadIdx.x & 63, w = threadIdx.x >> 6;
  double loc[N];
#pragma unroll
  for (int j = 0; j < N; ++j) {
    double x = v[j];
    for (int o = 32; o > 0; o >>= 1) x += __shfl_down(x, o);
    loc[j] = x;
  }
  if (lane == 0)
    for (int j = 0; j < N; ++j) sh[j][w] = loc[j];
  __syncthreads();
  if (threadIdx.x == 0)
    for (int j = 0; j < N; ++j) atomicAdd(&dst[j], sh[j][0] + sh[j][1] + sh[j][2] + sh[j][3]);
}

__device__ inline void rowstat(const float* __restrict__ row, int& am, float& conf) {
  float v[10];
  const float2* r2 = (const float2*)row;
#pragma unroll
  for (int j = 0; j < 5; ++j) { float2 x = r2[j]; v[2 * j] = x.x; v[2 * j + 1] = x.y; }
  float m = v[0]; int a = 0;
#pragma unroll
  for (int j = 1; j < 10; ++j) if (v[j] > m) { m = v[j]; a = j; }   // first max, like jnp.argmax
  float s = 0.f;
#pragma unroll
  for (int j = 0; j < 10; ++j) s += expf(v[j] - m);
  am = a;
  conf = 1.0f / s;   // max softmax value
}

__global__ __launch_bounds__(256)
void k_pos(const float* __restrict__ et, const float* __restrict__ ef,
           const float* __restrict__ probs,
           const float* __restrict__ pto, const float* __restrict__ pfr,
           int* __restrict__ amax_t, float* __restrict__ conf_t,
           int* __restrict__ amax_f, float* __restrict__ conf_f,
           float* __restrict__ posd, double* __restrict__ acc) {
  int i = blockIdx.x * 256 + threadIdx.x;
  int at, af; float ct, cf;
  rowstat(pto + (size_t)i * 10, at, ct);
  rowstat(pfr + (size_t)i * 10, af, cf);
  amax_t[i] = at; conf_t[i] = ct; amax_f[i] = af; conf_f[i] = cf;
  float2 a = ((const float2*)et)[i];
  float2 b = ((const float2*)ef)[i];
  float dx = a.x - b.x, dy = a.y - b.y;
  float d = sqrtf(dx * dx + dy * dy);
  posd[i] = (at == af) ? -d : d;          // sign bit encodes is_pred_same (−0.0 works)
  float pr = probs[i];
  float p  = 1.0f / (1.0f + d * d);
  float pc = fminf(fmaxf(p, 1e-4f), 1.0f);
  float qc = fminf(fmaxf(1.0f - p, 1e-4f), 1.0f);
  float ce = -pr * logf(pc) - (1.0f - pr) * logf(qc);
  double v[2] = {(double)d, (double)ce};
  block_acc<2>(acc + 0, v);
}

__global__ __launch_bounds__(256)
void k_neg(const float* __restrict__ et, const float* __restrict__ ef,
           const unsigned* __restrict__ perm,
           const int* __restrict__ amax_t, const float* __restrict__ conf_t,
           const int* __restrict__ amax_f, const float* __restrict__ conf_f,
           double* __restrict__ acc) {
  int i = blockIdx.x * 256 + threadIdx.x;
  unsigned pv = perm[i];
  int b = (int)(pv / 5u);
  int a = i / 5;
  float2 ta = ((const float2*)et)[a];
  float2 fb = ((const float2*)ef)[b];
  float dx = ta.x - fb.x, dy = ta.y - fb.y;
  float d = sqrtf(dx * dx + dy * dy);
  bool keep = !((amax_f[b] == amax_t[a]) && (conf_f[b] == conf_t[a]));
  float p  = 1.0f / (1.0f + d * d);
  float qc = fminf(fmaxf(1.0f - p, 1e-4f), 1.0f);
  float ce = -logf(qc);
  double v[3] = {keep ? (double)d : 0.0, keep ? (double)ce : 0.0, keep ? 1.0 : 0.0};
  block_acc<3>(acc + 2, v);
}

__global__ __launch_bounds__(256)
void k_margin(const float* __restrict__ posd, double* __restrict__ acc) {
  int i = blockIdx.x * 256 + threadIdx.x;
  float pm = (float)(acc[0] / (double)B_ROWS);
  float nm = (float)(acc[2] / acc[4]);
  float bm = (pm + nm) * 0.5f;
  float pd = posd[i];
  float c = 0.f;
  if (!(__float_as_uint(pd) >> 31)) c = fmaxf(bm - pd, 0.0f);
  double v[1] = {(double)c};
  block_acc<1>(acc + 5, v);
}

__global__ void k_final(const double* __restrict__ acc, float* __restrict__ out) {
  float ce_mean = (float)((acc[1] + acc[3]) / ((double)B_ROWS + acc[4]));
  float ml = (float)(acc[5] / (double)B_ROWS);
  out[0] = ce_mean + ml;
}

extern "C" void kernel_launch(void* const* d_in, const int* in_sizes, int n_in,
                              void* d_out, int out_size, void* d_ws, size_t ws_size,
                              hipStream_t stream) {
  const float* et  = (const float*)d_in[0];
  const float* ef  = (const float*)d_in[1];
  const float* pr  = (const float*)d_in[2];
  const float* pto = (const float*)d_in[3];
  const float* pfr = (const float*)d_in[4];
  float* out = (float*)d_out;
  if (ws_size < WS_NEEDED) return;   // diagnosable: output stays poisoned

  char* ws = (char*)d_ws;
  unsigned* K[2] = {(unsigned*)(ws + OFF_K0), (unsigned*)(ws + OFF_K1)};
  unsigned* V[2] = {(unsigned*)(ws + OFF_V0), (unsigned*)(ws + OFF_V1)};
  unsigned* hist = (unsigned*)(ws + OFF_HIST);
  unsigned* tot  = (unsigned*)(ws + OFF_TOT);
  unsigned* totx = (unsigned*)(ws + OFF_TOTX);
  int*    amax_t = (int*)(ws + OFF_AMAXT);
  float*  conf_t = (float*)(ws + OFF_CONFT);
  int*    amax_f = (int*)(ws + OFF_AMAXF);
  float*  conf_f = (float*)(ws + OFF_CONFF);
  float*  posd   = (float*)(ws + OFF_POSD);
  double* acc    = (double*)(ws + OFF_ACC);

  hipMemsetAsync(acc, 0, 8 * sizeof(double), stream);

  k_pos<<<B_ROWS / 256, 256, 0, stream>>>(et, ef, pr, pto, pfr,
                                          amax_t, conf_t, amax_f, conf_f, posd, acc);

  // Host-side threefry split chain (jax typed key(1) = [0,1]; foldlike split):
  //   round-1: key1 = cipher(key,(0,0)), subkey1 = cipher(key,(0,1))
  //   round-2: subkey2 = cipher(key1,(0,1))
  U2 key  = {0u, 1u};
  U2 key1 = tf2x32(key.a, key.b, 0u, 0u);
  U2 sk1  = tf2x32(key.a, key.b, 0u, 1u);
  U2 sk2  = tf2x32(key1.a, key1.b, 0u, 1u);

  int cur = 0;
  for (int round = 0; round < 2; ++round) {
    U2 sk = (round == 0) ? sk1 : sk2;
    k_keygen<<<N_NEG / 256, 256, 0, stream>>>(K[cur], V[cur], sk.a, sk.b, round == 0 ? 1 : 0);
    for (int pass = 0; pass < 4; ++pass) {
      int shift = pass * 8;
      k_hist<<<SBLK, 256, 0, stream>>>(K[cur], hist, shift);
      k_scan_rows<<<256, 64, 0, stream>>>(hist, tot);
      k_scan_totals<<<1, 256, 0, stream>>>(tot, totx);
      k_scatter<<<SBLK, 256, 0, stream>>>(K[cur], V[cur], K[cur ^ 1], V[cur ^ 1], hist, totx, shift);
      cur ^= 1;
    }
  }
  // cur == 0; final permutation lives in V[0]
  k_neg<<<N_NEG / 256, 256, 0, stream>>>(et, ef, V[cur], amax_t, conf_t, amax_f, conf_f, acc);
  k_margin<<<B_ROWS / 256, 256, 0, stream>>>(posd, acc);
  k_final<<<1, 1, 0, stream>>>(acc, out);
}

// Round 2
// 188.039 us; speedup vs baseline: 2.8165x; 2.8165x over previous
//
#include <hip/hip_runtime.h>

typedef unsigned long long u64;
typedef unsigned u32;

#define B_ROWS  262144
#define N_NEG   1310720
#define NB      4096          // buckets (12-bit, key>>20)
#define NCHUNK  128           // scatter/hist chunks
#define EPC     10240         // N_NEG / NCHUNK
#define EPT     40            // EPC / 256
#define CAP     512           // bitonic size per bucket (max realized ~430)

// ---------------- ws layout (bytes) ----------------
#define OFF_PAIRS   0u          // N_NEG * 8
#define OFF_INTERM  10485760u   // N_NEG * 4
#define OFF_HIST    15728640u   // 2*128*4096*4 = 4194304   layout [r][chunk][bucket]
#define OFF_TOT     19922944u   // 8192*4
#define OFF_TOTX    19955712u   // 8192*4
#define OFF_STATT   19988480u   // 262144*8 packed (amax<<32)|conf_bits
#define OFF_STATF   22085632u   // 262144*8
#define OFF_POSD    24182784u   // 262144*4
#define OFF_SLOTS   25231360u   // 6*256*8 = 12288
#define OFF_ACC     25243648u   // 8 doubles
#define WS_NEEDED   25243712u

struct U2 { unsigned a, b; };

// Threefry-2x32, 20 rounds — matches jax/_src/prng.py threefry2x32.
__host__ __device__ inline U2 tf2x32(unsigned k0, unsigned k1, unsigned c0, unsigned c1) {
  unsigned ks2 = k0 ^ k1 ^ 0x1BD11BDAu;
  unsigned x0 = c0 + k0, x1 = c1 + k1;
#define ROTL(x,d) (((x) << (d)) | ((x) >> (32 - (d))))
#define R4(r0,r1,r2,r3) \
  x0 += x1; x1 = ROTL(x1, r0); x1 ^= x0; \
  x0 += x1; x1 = ROTL(x1, r1); x1 ^= x0; \
  x0 += x1; x1 = ROTL(x1, r2); x1 ^= x0; \
  x0 += x1; x1 = ROTL(x1, r3); x1 ^= x0;
  R4(13,15,26,6)   x0 += k1;  x1 += ks2 + 1u;
  R4(17,29,16,24)  x0 += ks2; x1 += k0  + 2u;
  R4(13,15,26,6)   x0 += k0;  x1 += k1  + 3u;
  R4(17,29,16,24)  x0 += k1;  x1 += ks2 + 4u;
  R4(13,15,26,6)   x0 += ks2; x1 += k0  + 5u;
#undef R4
#undef ROTL
  return U2{x0, x1};
}

__device__ inline u32 keyfn(unsigned k0, unsigned k1, u32 i) {
  U2 c = tf2x32(k0, k1, 0u, i);
  return c.a ^ c.b;
}

// ---------- block reduce: thread 0 ends with totals in v[] ----------
template <int N>
__device__ inline void block_sum(double* v) {
  __shared__ double sh[N][4];
  int lane = threadIdx.x & 63, w = threadIdx.x >> 6;
#pragma unroll
  for (int j = 0; j < N; ++j) {
    double x = v[j];
    for (int o = 32; o > 0; o >>= 1) x += __shfl_down(x, o);
    if (lane == 0) sh[j][w] = x;
  }
  __syncthreads();
  if (threadIdx.x == 0)
#pragma unroll
    for (int j = 0; j < N; ++j) v[j] = sh[j][0] + sh[j][1] + sh[j][2] + sh[j][3];
  __syncthreads();
}

// ---------------- sort pipeline ----------------

// both rounds' histograms; keys computed on the fly
__global__ __launch_bounds__(256)
void k_hist(u32* __restrict__ hist, unsigned k10, unsigned k11, unsigned k20, unsigned k21) {
  __shared__ u32 h[2][NB];
  int t = threadIdx.x, blk = blockIdx.x;
  for (int b = t; b < 2 * NB; b += 256) ((u32*)h)[b] = 0;
  __syncthreads();
  u32 base = blk * EPC;
#pragma unroll 4
  for (int e = 0; e < EPT; ++e) {
    u32 i = base + e * 256 + t;
    atomicAdd(&h[0][keyfn(k10, k11, i) >> 20], 1u);
    atomicAdd(&h[1][keyfn(k20, k21, i) >> 20], 1u);
  }
  __syncthreads();
  for (int b = t; b < NB; b += 256) {
    hist[(size_t)blk * NB + b] = h[0][b];                        // r=0
    hist[(size_t)(NCHUNK + blk) * NB + b] = h[1][b];             // r=1
  }
}

// exclusive scan over chunks, per digit; 64 digits per block, sequential over chunks
__global__ void k_scan_rows(u32* __restrict__ hist, u32* __restrict__ tot) {
  int lane = threadIdx.x;                       // 64
  int r = blockIdx.x >> 6;                      // 128 blocks: r = blk/64
  int d0 = (blockIdx.x & 63) * 64;
  u32 running = 0;
  for (int c = 0; c < NCHUNK; ++c) {
    size_t idx = ((size_t)r * NCHUNK + c) * NB + d0 + lane;
    u32 v = hist[idx];
    hist[idx] = running;
    running += v;
  }
  tot[r * NB + d0 + lane] = running;
}

// exclusive scan of bucket totals (4096 per round)
__global__ void k_scan_tot(const u32* __restrict__ tot, u32* __restrict__ totx) {
  int r = blockIdx.x, t = threadIdx.x;
  const u32* src = tot + r * NB;
  u32* dst = totx + r * NB;
  u32 loc[16];
  u32 s = 0;
#pragma unroll
  for (int q = 0; q < 16; ++q) { loc[q] = src[t * 16 + q]; s += loc[q]; }
  __shared__ u32 sh[256];
  sh[t] = s;
  __syncthreads();
  for (int o = 1; o < 256; o <<= 1) {
    u32 x = (t >= o) ? sh[t - o] : 0u;
    __syncthreads();
    sh[t] += x;
    __syncthreads();
  }
  u32 run = sh[t] - s;
#pragma unroll
  for (int q = 0; q < 16; ++q) { dst[t * 16 + q] = run; run += loc[q]; }
}

// scatter (key,idx) pairs into bucket-contiguous slots; no global atomics
__global__ __launch_bounds__(256)
void k_scatter(u64* __restrict__ pairs, const u32* __restrict__ histR,
               const u32* __restrict__ totxR, unsigned k0, unsigned k1) {
  __shared__ u32 cur[NB];
  int t = threadIdx.x, blk = blockIdx.x;
  for (int b = t; b < NB; b += 256)
    cur[b] = totxR[b] + histR[(size_t)blk * NB + b];
  __syncthreads();
  u32 base = blk * EPC;
#pragma unroll 4
  for (int e = 0; e < EPT; ++e) {
    u32 i = base + e * 256 + t;
    u32 key = keyfn(k0, k1, i);
    u32 slot = atomicAdd(&cur[key >> 20], 1u);
    pairs[slot] = ((u64)key << 32) | i;
  }
}

__device__ inline void bitonic512(u64* sh, int t) {
  for (int k = 2; k <= CAP; k <<= 1)
    for (int j = k >> 1; j > 0; j >>= 1) {
      __syncthreads();
#pragma unroll
      for (int q = 0; q < 2; ++q) {
        int ii = t + q * 256;
        int l = ii ^ j;
        if (l > ii) {
          u64 a = sh[ii], b = sh[l];
          bool up = ((ii & k) == 0);
          if ((a > b) == up) { sh[ii] = b; sh[l] = a; }
        }
      }
    }
  __syncthreads();
}

// round-1 bucket sort: write interm[pos] = original index
__global__ __launch_bounds__(256)
void k_bsort1(const u64* __restrict__ pairs, const u32* __restrict__ tot,
              const u32* __restrict__ totx, u32* __restrict__ interm) {
  __shared__ u64 sh[CAP];
  int t = threadIdx.x, b = blockIdx.x;
  u32 base = totx[b], c = tot[b];
#pragma unroll
  for (int q = 0; q < 2; ++q) {
    int ii = t + q * 256;
    sh[ii] = (ii < (int)c) ? pairs[base + ii] : ~0ull;
  }
  bitonic512(sh, t);
#pragma unroll
  for (int q = 0; q < 2; ++q) {
    int ii = t + q * 256;
    if (ii < (int)c) interm[base + ii] = (u32)sh[ii];
  }
}

// round-2 bucket sort fused with negative-pair loss
__global__ __launch_bounds__(256)
void k_bsort2_loss(const u64* __restrict__ pairs, const u32* __restrict__ tot,
                   const u32* __restrict__ totx, const u32* __restrict__ interm,
                   const float* __restrict__ et, const float* __restrict__ ef,
                   const u64* __restrict__ statT, const u64* __restrict__ statF,
                   double* __restrict__ slots) {
  __shared__ u64 sh[CAP];
  int t = threadIdx.x, b = blockIdx.x;
  u32 base = totx[b], c = tot[b];
#pragma unroll
  for (int q = 0; q < 2; ++q) {
    int ii = t + q * 256;
    sh[ii] = (ii < (int)c) ? pairs[base + ii] : ~0ull;
  }
  bitonic512(sh, t);
  double sd = 0.0, sce = 0.0, sn = 0.0;
#pragma unroll
  for (int q = 0; q < 2; ++q) {
    int ii = t + q * 256;
    if (ii < (int)c) {
      u32 j = (u32)sh[ii];
      u32 p = base + ii;          // final position
      u32 i = interm[j];          // original repeat index
      u32 a = p / 5u;             // to-row
      u32 bb = i / 5u;            // from-row
      float2 ta = ((const float2*)et)[a];
      float2 fb = ((const float2*)ef)[bb];
      float dx = ta.x - fb.x, dy = ta.y - fb.y;
      float d = sqrtf(dx * dx + dy * dy);
      u64 st = statT[a], sf = statF[bb];
      int at = (int)(st >> 32), af = (int)(sf >> 32);
      float ct = __uint_as_float((u32)st), cf = __uint_as_float((u32)sf);
      bool keep = !((af == at) && (cf == ct));
      float pp = 1.0f / (1.0f + d * d);
      float qc = fminf(fmaxf(1.0f - pp, 1e-4f), 1.0f);
      float ce = -logf(qc);
      if (keep) { sd += (double)d; sce += (double)ce; sn += 1.0; }
    }
  }
  double v[3] = {sd, sce, sn};
  block_sum<3>(v);
  if (t == 0) {
    int slot = b & 255;
    atomicAdd(&slots[2 * 256 + slot], v[0]);
    atomicAdd(&slots[3 * 256 + slot], v[1]);
    atomicAdd(&slots[4 * 256 + slot], v[2]);
  }
}

// ---------------- loss kernels ----------------
__device__ inline void rowstat(const float* __restrict__ row, int& am, float& conf) {
  float v[10];
  const float2* r2 = (const float2*)row;
#pragma unroll
  for (int j = 0; j < 5; ++j) { float2 x = r2[j]; v[2 * j] = x.x; v[2 * j + 1] = x.y; }
  float m = v[0]; int a = 0;
#pragma unroll
  for (int j = 1; j < 10; ++j) if (v[j] > m) { m = v[j]; a = j; }   // first max, like jnp.argmax
  float s = 0.f;
#pragma unroll
  for (int j = 0; j < 10; ++j) s += expf(v[j] - m);
  am = a;
  conf = 1.0f / s;
}

__global__ __launch_bounds__(256)
void k_pos(const float* __restrict__ et, const float* __restrict__ ef,
           const float* __restrict__ probs,
           const float* __restrict__ pto, const float* __restrict__ pfr,
           u64* __restrict__ statT, u64* __restrict__ statF,
           float* __restrict__ posd, double* __restrict__ slots) {
  int i = blockIdx.x * 256 + threadIdx.x;
  int at, af; float ct, cf;
  rowstat(pto + (size_t)i * 10, at, ct);
  rowstat(pfr + (size_t)i * 10, af, cf);
  statT[i] = ((u64)(u32)at << 32) | (u64)__float_as_uint(ct);
  statF[i] = ((u64)(u32)af << 32) | (u64)__float_as_uint(cf);
  float2 a = ((const float2*)et)[i];
  float2 b = ((const float2*)ef)[i];
  float dx = a.x - b.x, dy = a.y - b.y;
  float d = sqrtf(dx * dx + dy * dy);
  posd[i] = (at == af) ? -d : d;          // sign bit encodes is_pred_same
  float pr = probs[i];
  float p  = 1.0f / (1.0f + d * d);
  float pc = fminf(fmaxf(p, 1e-4f), 1.0f);
  float qc = fminf(fmaxf(1.0f - p, 1e-4f), 1.0f);
  float ce = -pr * logf(pc) - (1.0f - pr) * logf(qc);
  double v[2] = {(double)d, (double)ce};
  block_sum<2>(v);
  if (threadIdx.x == 0) {
    int slot = blockIdx.x & 255;
    atomicAdd(&slots[0 * 256 + slot], v[0]);
    atomicAdd(&slots[1 * 256 + slot], v[1]);
  }
}

// collapse slots 0..4 into acc scalars
__global__ void k_collapse(const double* __restrict__ slots, double* __restrict__ acc) {
  int t = threadIdx.x;
  for (int q = 0; q < 5; ++q) {
    double v[1] = { slots[q * 256 + t] };
    block_sum<1>(v);
    if (t == 0) acc[q] = v[0];
  }
}

__global__ __launch_bounds__(256)
void k_margin(const float* __restrict__ posd, const double* __restrict__ acc,
              double* __restrict__ slots) {
  int i = blockIdx.x * 256 + threadIdx.x;
  float pm = (float)(acc[0] / (double)B_ROWS);
  float nm = (float)(acc[2] / acc[4]);
  float bm = (pm + nm) * 0.5f;
  float pd = posd[i];
  float c = 0.f;
  if (!(__float_as_uint(pd) >> 31)) c = fmaxf(bm - pd, 0.0f);
  double v[1] = {(double)c};
  block_sum<1>(v);
  if (threadIdx.x == 0) atomicAdd(&slots[5 * 256 + (blockIdx.x & 255)], v[0]);
}

__global__ void k_final(const double* __restrict__ slots, const double* __restrict__ acc,
                        float* __restrict__ out) {
  int t = threadIdx.x;
  double v[1] = { slots[5 * 256 + t] };
  block_sum<1>(v);
  if (t == 0) {
    float ce_mean = (float)((acc[1] + acc[3]) / ((double)B_ROWS + acc[4]));
    float ml = (float)(v[0] / (double)B_ROWS);
    out[0] = ce_mean + ml;
  }
}

extern "C" void kernel_launch(void* const* d_in, const int* in_sizes, int n_in,
                              void* d_out, int out_size, void* d_ws, size_t ws_size,
                              hipStream_t stream) {
  const float* et  = (const float*)d_in[0];
  const float* ef  = (const float*)d_in[1];
  const float* pr  = (const float*)d_in[2];
  const float* pto = (const float*)d_in[3];
  const float* pfr = (const float*)d_in[4];
  float* out = (float*)d_out;
  if (ws_size < WS_NEEDED) return;   // diagnosable: output stays poisoned

  char* ws = (char*)d_ws;
  u64* pairs   = (u64*)(ws + OFF_PAIRS);
  u32* interm  = (u32*)(ws + OFF_INTERM);
  u32* hist    = (u32*)(ws + OFF_HIST);
  u32* tot     = (u32*)(ws + OFF_TOT);
  u32* totx    = (u32*)(ws + OFF_TOTX);
  u64* statT   = (u64*)(ws + OFF_STATT);
  u64* statF   = (u64*)(ws + OFF_STATF);
  float* posd  = (float*)(ws + OFF_POSD);
  double* slots= (double*)(ws + OFF_SLOTS);
  double* acc  = (double*)(ws + OFF_ACC);

  hipMemsetAsync(slots, 0, 6 * 256 * sizeof(double) + 8 * sizeof(double), stream);

  // Host-side threefry split chain (jax typed key(1) = [0,1]):
  U2 key  = {0u, 1u};
  U2 key1 = tf2x32(key.a, key.b, 0u, 0u);
  U2 sk1  = tf2x32(key.a, key.b, 0u, 1u);
  U2 sk2  = tf2x32(key1.a, key1.b, 0u, 1u);

  k_pos<<<B_ROWS / 256, 256, 0, stream>>>(et, ef, pr, pto, pfr, statT, statF, posd, slots);

  k_hist<<<NCHUNK, 256, 0, stream>>>(hist, sk1.a, sk1.b, sk2.a, sk2.b);
  k_scan_rows<<<128, 64, 0, stream>>>(hist, tot);
  k_scan_tot<<<2, 256, 0, stream>>>(tot, totx);

  // round 1
  k_scatter<<<NCHUNK, 256, 0, stream>>>(pairs, hist, totx, sk1.a, sk1.b);
  k_bsort1<<<NB, 256, 0, stream>>>(pairs, tot, totx, interm);
  // round 2 (+ fused negative loss)
  k_scatter<<<NCHUNK, 256, 0, stream>>>(pairs, hist + (size_t)NCHUNK * NB, totx + NB, sk2.a, sk2.b);
  k_bsort2_loss<<<NB, 256, 0, stream>>>(pairs, tot + NB, totx + NB, interm,
                                        et, ef, statT, statF, slots);

  k_collapse<<<1, 256, 0, stream>>>(slots, acc);
  k_margin<<<B_ROWS / 256, 256, 0, stream>>>(posd, acc, slots);
  k_final<<<1, 256, 0, stream>>>(slots, acc, out);
}